// Round 17
// baseline (98.548 us; speedup 1.0000x reference)
//
#include <hip/hip_runtime.h>
#include <hip/hip_bf16.h>

#define D_MODEL 256
#define LQ 4800
#define NB 2
#define MROWS (NB * LQ)       // 9600
#define LN_EPS 1e-5f

typedef unsigned int u32;
typedef unsigned short u16;
typedef __attribute__((ext_vector_type(8))) short bf16x8;
typedef __attribute__((ext_vector_type(4))) float f32x4;
typedef __attribute__((ext_vector_type(4))) u32 u32x4;
typedef __attribute__((ext_vector_type(2))) _Float16 f16x2;
typedef __attribute__((ext_vector_type(8))) _Float16 f16x8;

__device__ __forceinline__ u16 f2bf(float f) {
    __hip_bfloat16 h = __float2bfloat16(f);
    return *reinterpret_cast<u16*>(&h);
}
__device__ __forceinline__ float bf2f(u32 bits16) {
    return __uint_as_float(bits16 << 16);
}

// f16 pair dot into f32 (v_dot2_f32_f16)
__device__ __forceinline__ float dot2f16(u32 a, u32 b, float c) {
#if __has_builtin(__builtin_amdgcn_fdot2)
    return __builtin_amdgcn_fdot2(__builtin_bit_cast(f16x2, a),
                                  __builtin_bit_cast(f16x2, b), c, false);
#else
    f16x2 av = __builtin_bit_cast(f16x2, a), bv = __builtin_bit_cast(f16x2, b);
    c = fmaf((float)av.x, (float)bv.x, c);
    return fmaf((float)av.y, (float)bv.y, c);
#endif
}
__device__ __forceinline__ u32 pk_fma16(u32 a, u32 b, u32 c) {
    u32 d;
    asm("v_pk_fma_f16 %0, %1, %2, %3" : "=v"(d) : "v"(a), "v"(b), "v"(c));
    return d;
}
__device__ __forceinline__ u32 pk_add16(u32 a, u32 b) {
    u32 d;
    asm("v_pk_add_f16 %0, %1, %2" : "=v"(d) : "v"(a), "v"(b));
    return d;
}
__device__ __forceinline__ u32 pkrtz(float a, float b) {
    return __builtin_bit_cast(u32, __builtin_amdgcn_cvt_pkrtz(a, b));
}
__device__ __forceinline__ void gload_lds(const u16* src, u16* dst) {
    __builtin_amdgcn_global_load_lds(
        (const __attribute__((address_space(1))) u32*)src,
        (__attribute__((address_space(3))) u32*)dst, 16, 0, 0);
}
__device__ __forceinline__ void gload_lds_f32(const float* src, u32* dst) {
    __builtin_amdgcn_global_load_lds(
        (const __attribute__((address_space(1))) u32*)src,
        (__attribute__((address_space(3))) u32*)dst, 16, 0, 0);
}

// ---------------------------------------------------------------------------
// Prep: weight transposes only. grid 2560.
//  [0,768)    Wq|Wk|Wv -> Wqkvh (f16) rows 0..767
//  [768,1024) Wm -> Wmt (bf16)
//  [1024,2048) W1: k<256 -> Wqkvh (f16) rows 768..1279; k>=256 -> W1bt bf16
//  [2048,2560) W2 -> W2t (bf16, ldt 512)
// ---------------------------------------------------------------------------
__global__ __launch_bounds__(256) void prep_kernel(
    const float* __restrict__ Wq, const float* __restrict__ Wk,
    const float* __restrict__ Wv, const float* __restrict__ Wm,
    const float* __restrict__ W1, const float* __restrict__ W2,
    u16* __restrict__ Wqkvh, u16* __restrict__ Wmt,
    u16* __restrict__ W1bt, u16* __restrict__ W2t)
{
    __shared__ float tile[16][17];
    const int t = threadIdx.x, tx = t & 15, ty = t >> 4;
    int sub = blockIdx.x;

    const float* W; int Nd, tn, tk, drow, dcol, ldt; u16* dst; bool f16o = false;
    if (sub < 768) {
        W = sub < 256 ? Wq : (sub < 512 ? Wk : Wv);
        int s = sub & 255; Nd = 256; tn = s % 16; tk = s / 16;
        dst = Wqkvh; drow = (sub >> 8) * 256 + tn * 16; dcol = tk * 16; ldt = 256; f16o = true;
    } else if (sub < 1024) {
        W = Wm; int s = sub - 768; Nd = 256; tn = s % 16; tk = s / 16;
        dst = Wmt; drow = tn * 16; dcol = tk * 16; ldt = 256;
    } else if (sub < 2048) {
        W = W1; int s = sub - 1024; Nd = 512; tn = s % 32; tk = s / 32;
        if (tk < 16) { dst = Wqkvh; drow = 768 + tn * 16; dcol = tk * 16; ldt = 256; f16o = true; }
        else         { dst = W1bt;  drow = tn * 16; dcol = (tk - 16) * 16; ldt = 256; }
    } else {
        W = W2; int s = sub - 2048; Nd = 256; tn = s % 16; tk = s / 16;
        dst = W2t; drow = tn * 16; dcol = tk * 16; ldt = 512;
    }
    tile[ty][tx] = W[(size_t)(tk * 16 + ty) * Nd + tn * 16 + tx];
    __syncthreads();
    float v = tile[tx][ty];
    u16 o;
    if (f16o) { _Float16 h = (_Float16)v; o = __builtin_bit_cast(u16, h); }
    else      o = f2bf(v);
    dst[(size_t)(drow + ty) * ldt + dcol + tx] = o;
}

// ---------------------------------------------------------------------------
// qkv+h_top GEMM: [q|k|v|h_top] = A_fp32 @ Wqkvh^T (f16 MFMA, K=256, N=1280).
// 2-phase double-buffered staging: issue tile t+1's loads before computing
// tile t; one barrier per tile (its vmcnt drain overlaps the MFMA phase).
// ---------------------------------------------------------------------------
__global__ __launch_bounds__(256) void qkvh_kernel(
    const float* __restrict__ x, const float* __restrict__ source,
    const u16* __restrict__ Wqkvh,
    u16* __restrict__ qkvb, u16* __restrict__ hx)
{
    __shared__ __align__(16) float As32[2][64 * 32];   // 2 x 8 KB
    __shared__ __align__(16) u16 Bs[2][128 * 32];      // 2 x 8 KB

    const int t = threadIdx.x, l = t & 63, w = t >> 6;
    const int m0 = blockIdx.y * 64, n0 = blockIdx.x * 128;
    const int wr = w >> 1, wc = w & 1;
    const float* Ap = (n0 < 256 || n0 >= 768) ? x : source;

    const int srow = l >> 2, sch = (l & 3) ^ (srow & 3);   // B staging
    const int arow8 = l >> 3, acw = (l & 7) ^ (arow8 & 7); // A staging (fp32)
    const int r = l & 15, ch = l >> 4;

    auto stage = [&](int k0, int b_) {
#pragma unroll
        for (int h = 0; h < 2; ++h) {
            const float* asrc = Ap + (size_t)(m0 + w * 16 + h * 8 + arow8) * 256 + k0 + acw * 4;
            gload_lds_f32(asrc, (u32*)As32[b_] + w * 512 + h * 256);
        }
#pragma unroll
        for (int g = 0; g < 2; ++g) {
            int grp = w * 2 + g;
            gload_lds(Wqkvh + (size_t)(n0 + grp * 16 + srow) * 256 + k0 + sch * 8,
                      Bs[b_] + grp * 512);
        }
    };

    f32x4 acc[2][4];
#pragma unroll
    for (int i = 0; i < 2; ++i)
#pragma unroll
        for (int j = 0; j < 4; ++j) acc[i][j] = (f32x4){0.f, 0.f, 0.f, 0.f};

    stage(0, 0);
    __syncthreads();
    int cur = 0;
    for (int tt = 0; tt < 8; ++tt) {
        if (tt + 1 < 8) stage((tt + 1) * 32, cur ^ 1);

        f16x8 af[2];
#pragma unroll
        for (int i = 0; i < 2; ++i) {
            int ar = wr * 32 + i * 16 + r;
            int s0 = (2 * ch) ^ (ar & 7), s1 = (2 * ch + 1) ^ (ar & 7);
            f32x4 alo = *(const f32x4*)((const char*)As32[cur] + ar * 128 + s0 * 16);
            f32x4 ahi = *(const f32x4*)((const char*)As32[cur] + ar * 128 + s1 * 16);
            u32x4 pk = { pkrtz(alo.x, alo.y), pkrtz(alo.z, alo.w),
                         pkrtz(ahi.x, ahi.y), pkrtz(ahi.z, ahi.w) };
            af[i] = __builtin_bit_cast(f16x8, pk);
        }
#pragma unroll
        for (int j = 0; j < 4; ++j) {
            int br = wc * 64 + j * 16 + r;
            f16x8 bf = *(const f16x8*)((const char*)Bs[cur] + br * 64 + ((ch ^ (r & 3)) * 16));
#pragma unroll
            for (int i = 0; i < 2; ++i)
                acc[i][j] = __builtin_amdgcn_mfma_f32_16x16x32_f16(af[i], bf, acc[i][j], 0, 0, 0);
        }
        __syncthreads();
        cur ^= 1;
    }

    const int q4 = l >> 4;
#pragma unroll
    for (int i = 0; i < 2; ++i)
#pragma unroll
        for (int j = 0; j < 4; ++j) {
            int col = n0 + wc * 64 + j * 16 + r;
#pragma unroll
            for (int reg = 0; reg < 4; ++reg) {
                int row = m0 + wr * 32 + i * 16 + q4 * 4 + reg;
                float vv = acc[i][j][reg];
                if (col < 768) {
                    _Float16 hv = (_Float16)vv;
                    qkvb[(size_t)(col >> 8) * MROWS * 256 + (size_t)row * 256 + (col & 255)] =
                        __builtin_bit_cast(u16, hv);
                } else {
                    hx[(size_t)row * 512 + (col - 768)] = f2bf(vv);
                }
            }
        }
}

// ---------------------------------------------------------------------------
// Fused Wm+LN1+W1_bot: per 32-row block (300 blocks):
// Phase A (2-phase pipelined): msgln = LN1(msg @ Wm), kept in LDS (swizzled).
// Phase B: h1 = relu(msgln @ W1_bot + hx), A from LDS (no staging).
// BsM: phase A = two 16KB k-tile buffers; phase B = one 32KB 512-row tile.
// ---------------------------------------------------------------------------
__global__ __launch_bounds__(256) void wm_w1_kernel(
    const u16* __restrict__ msg, const u16* __restrict__ Wmt,
    const u16* __restrict__ W1bt, const u16* __restrict__ hx,
    const float* __restrict__ g1, const float* __restrict__ b1,
    u16* __restrict__ h1b)
{
    __shared__ __align__(16) u16 As[2][32 * 32];   // 2 x 2 KB
    __shared__ __align__(16) u16 BsM[2 * 256 * 32]; // 32 KB
    __shared__ __align__(16) u16 mln[32 * 256];    // 16 KB, XOR-8 swizzled
    __shared__ float2 red[32][2];

    const int t = threadIdx.x, l = t & 63, w = t >> 6;
    const int m0 = blockIdx.x * 32;
    const int srow = l >> 2, sch = (l & 3) ^ (srow & 3);
    const int r = l & 15, ch = l >> 4, q4 = l >> 4;

    // ================= Phase A (2x2 waves, FJ=8, 2-phase) ================
    {
        const int wr = w >> 1, wc = w & 1;

        auto stageA = [&](int k0, int b_) {
            if (w < 2)
                gload_lds(msg + (size_t)(m0 + w * 16 + srow) * 256 + k0 + sch * 8,
                          As[b_] + w * 512);
#pragma unroll
            for (int g = 0; g < 4; ++g) {
                int grp = w * 4 + g;
                gload_lds(Wmt + (size_t)(grp * 16 + srow) * 256 + k0 + sch * 8,
                          BsM + b_ * 8192 + grp * 512);
            }
        };

        f32x4 acc[8];
#pragma unroll
        for (int j = 0; j < 8; ++j) acc[j] = (f32x4){0.f, 0.f, 0.f, 0.f};

        stageA(0, 0);
        __syncthreads();
        int cur = 0;
        for (int tt = 0; tt < 8; ++tt) {
            if (tt + 1 < 8) stageA((tt + 1) * 32, cur ^ 1);
            bf16x8 af = *(const bf16x8*)((const char*)As[cur] + (wr * 16 + r) * 64 + ((ch ^ (r & 3)) * 16));
#pragma unroll
            for (int j = 0; j < 8; ++j) {
                int br = wc * 128 + j * 16 + r;
                bf16x8 bf = *(const bf16x8*)((const char*)BsM + cur * 16384 + br * 64 + ((ch ^ (r & 3)) * 16));
                acc[j] = __builtin_amdgcn_mfma_f32_16x16x32_bf16(af, bf, acc[j], 0, 0, 0);
            }
            __syncthreads();
            cur ^= 1;
        }

        float rs[4], rq[4];
#pragma unroll
        for (int reg = 0; reg < 4; ++reg) {
            float s = 0.f, sq = 0.f;
#pragma unroll
            for (int j = 0; j < 8; ++j) { float vv = acc[j][reg]; s += vv; sq += vv * vv; }
            rs[reg] = s; rq[reg] = sq;
        }
#pragma unroll
        for (int off = 1; off <= 8; off <<= 1)
#pragma unroll
            for (int reg = 0; reg < 4; ++reg) {
                rs[reg] += __shfl_xor(rs[reg], off);
                rq[reg] += __shfl_xor(rq[reg], off);
            }
        if (r == 0)
#pragma unroll
            for (int reg = 0; reg < 4; ++reg)
                red[wr * 16 + q4 * 4 + reg][wc] = make_float2(rs[reg], rq[reg]);
        __syncthreads();

#pragma unroll
        for (int reg = 0; reg < 4; ++reg) {
            int row = wr * 16 + q4 * 4 + reg;
            float sum = red[row][0].x + red[row][1].x;
            float sq  = red[row][0].y + red[row][1].y;
            float mu  = sum * 0.00390625f;
            float var = sq * 0.00390625f - mu * mu;
            float rstd = rsqrtf(var + LN_EPS);
#pragma unroll
            for (int j = 0; j < 8; ++j) {
                int col = wc * 128 + j * 16 + r;
                float vv = (acc[j][reg] - mu) * rstd * g1[col] + b1[col];
                int cc = col >> 3, slot = cc ^ (row & 7);
                *(u16*)((char*)mln + row * 512 + slot * 16 + (col & 7) * 2) = f2bf(vv);
            }
        }
        __syncthreads();
    }

    // ================= Phase B (1x4 waves, FI=2, FJ=8) ===================
    {
        f32x4 acc2[2][8];
#pragma unroll
        for (int i = 0; i < 2; ++i)
#pragma unroll
            for (int j = 0; j < 8; ++j) acc2[i][j] = (f32x4){0.f, 0.f, 0.f, 0.f};

        for (int k0 = 0; k0 < 256; k0 += 32) {
#pragma unroll
            for (int g = 0; g < 8; ++g) {
                int row = w * 128 + g * 16 + srow;
                gload_lds(W1bt + (size_t)row * 256 + k0 + sch * 8, BsM + (w * 8 + g) * 512);
            }
            __syncthreads();
            bf16x8 af2[2];
#pragma unroll
            for (int i = 0; i < 2; ++i) {
                int ar = i * 16 + r;
                int c0 = (k0 >> 3) + ch;
                af2[i] = *(const bf16x8*)((const char*)mln + ar * 512 + ((c0 ^ (ar & 7)) * 16));
            }
#pragma unroll
            for (int j = 0; j < 8; ++j) {
                int br = w * 128 + j * 16 + r;
                bf16x8 bf = *(const bf16x8*)((const char*)BsM + br * 64 + ((ch ^ (r & 3)) * 16));
#pragma unroll
                for (int i = 0; i < 2; ++i)
                    acc2[i][j] = __builtin_amdgcn_mfma_f32_16x16x32_bf16(af2[i], bf, acc2[i][j], 0, 0, 0);
            }
            __syncthreads();
        }

#pragma unroll
        for (int i = 0; i < 2; ++i)
#pragma unroll
            for (int j = 0; j < 8; ++j) {
                int col = w * 128 + j * 16 + r;
#pragma unroll
                for (int reg = 0; reg < 4; ++reg) {
                    int row = i * 16 + q4 * 4 + reg;
                    size_t oidx = (size_t)(m0 + row) * 512 + col;
                    float vv = acc2[i][j][reg] + bf2f((u32)hx[oidx]);
                    vv = fmaxf(vv, 0.f);
                    h1b[oidx] = f2bf(vv);
                }
            }
    }
}

// ---------------------------------------------------------------------------
// GEMM (32 rows, N=256) + fused LayerNorm epilogue, 2-phase pipelined.
// ---------------------------------------------------------------------------
template<bool RESID, bool OUT_BF16>
__global__ __launch_bounds__(256) void gemm_ln_kernel(
    const u16* __restrict__ A, int lda,
    const u16* __restrict__ Bt, int ldb,
    const float* __restrict__ g, const float* __restrict__ b,
    const float* __restrict__ xres,
    void* __restrict__ Cout, int K)
{
    __shared__ __align__(16) u16 As[2][32 * 32];    // 2 x 2 KB
    __shared__ __align__(16) u16 Bs[2][256 * 32];   // 2 x 16 KB
    __shared__ float2 red[32][2];

    const int t  = threadIdx.x, l = t & 63, w = t >> 6;
    const int m0 = blockIdx.x * 32;
    const int wr = w >> 1, wc = w & 1;
    const int srow = l >> 2, sch = (l & 3) ^ (srow & 3);
    const int r = l & 15, ch = l >> 4, q4 = l >> 4;

    auto stage = [&](int k0, int b_) {
        if (w < 2)
            gload_lds(A + (size_t)(m0 + w * 16 + srow) * lda + k0 + sch * 8, As[b_] + w * 512);
#pragma unroll
        for (int gg = 0; gg < 4; ++gg) {
            int grp = w * 4 + gg;
            gload_lds(Bt + (size_t)(grp * 16 + srow) * ldb + k0 + sch * 8, Bs[b_] + grp * 512);
        }
    };

    f32x4 acc[8];
#pragma unroll
    for (int j = 0; j < 8; ++j) acc[j] = (f32x4){0.f, 0.f, 0.f, 0.f};

    const int NT = K / 32;
    stage(0, 0);
    __syncthreads();
    int cur = 0;
    for (int tt = 0; tt < NT; ++tt) {
        if (tt + 1 < NT) stage((tt + 1) * 32, cur ^ 1);
        bf16x8 af = *(const bf16x8*)((const char*)As[cur] + (wr * 16 + r) * 64 + ((ch ^ (r & 3)) * 16));
#pragma unroll
        for (int j = 0; j < 8; ++j) {
            int br = wc * 128 + j * 16 + r;
            bf16x8 bf = *(const bf16x8*)((const char*)Bs[cur] + br * 64 + ((ch ^ (r & 3)) * 16));
            acc[j] = __builtin_amdgcn_mfma_f32_16x16x32_bf16(af, bf, acc[j], 0, 0, 0);
        }
        __syncthreads();
        cur ^= 1;
    }

    float rs[4], rq[4];
#pragma unroll
    for (int reg = 0; reg < 4; ++reg) {
        float s = 0.f, sq = 0.f;
#pragma unroll
        for (int j = 0; j < 8; ++j) { float vv = acc[j][reg]; s += vv; sq += vv * vv; }
        rs[reg] = s; rq[reg] = sq;
    }
#pragma unroll
    for (int off = 1; off <= 8; off <<= 1)
#pragma unroll
        for (int reg = 0; reg < 4; ++reg) {
            rs[reg] += __shfl_xor(rs[reg], off);
            rq[reg] += __shfl_xor(rq[reg], off);
        }
    if (r == 0)
#pragma unroll
        for (int reg = 0; reg < 4; ++reg)
            red[wr * 16 + q4 * 4 + reg][wc] = make_float2(rs[reg], rq[reg]);
    __syncthreads();

    float gj[8], bj[8];
#pragma unroll
    for (int j = 0; j < 8; ++j) {
        int col = wc * 128 + j * 16 + r;
        gj[j] = g[col]; bj[j] = b[col];
    }

#pragma unroll
    for (int reg = 0; reg < 4; ++reg) {
        int row = wr * 16 + q4 * 4 + reg;
        float sum = red[row][0].x + red[row][1].x;
        float sq  = red[row][0].y + red[row][1].y;
        float mu  = sum * 0.00390625f;
        float var = sq * 0.00390625f - mu * mu;
        float rstd = rsqrtf(var + LN_EPS);
#pragma unroll
        for (int j = 0; j < 8; ++j) {
            int col = wc * 128 + j * 16 + r;
            float vv = (acc[j][reg] - mu) * rstd * gj[j] + bj[j];
            size_t oidx = (size_t)(m0 + row) * 256 + col;
            if (RESID) vv += xres[oidx];
            if (OUT_BF16) ((u16*)Cout)[oidx] = f2bf(vv);
            else          ((float*)Cout)[oidx] = vv;
        }
    }
}

// ---------------------------------------------------------------------------
// Gathered attention: wave = (query, head-pair), 128B oct-coalesced gathers.
// XCD batch-affinity relabel. At the random-gather L2 floor (~34 us).
// ---------------------------------------------------------------------------
__global__ __launch_bounds__(256, 8) void attn_kernel(
    const u16* __restrict__ q, const u16* __restrict__ k,
    const u16* __restrict__ v, const int* __restrict__ idx,
    u16* __restrict__ msg)
{
    const int t  = threadIdx.x;
    const int l  = t & 63;
    const int hp = t >> 6;
    const int bid = blockIdx.x;
    const int x8 = bid & 7, jj = bid >> 3;
    const int qi = (x8 < 4) ? (x8 * 1200 + jj) : (LQ + (x8 - 4) * 1200 + jj);
    const int n  = qi / LQ;
    const size_t srcbase = (size_t)n * LQ * 256;

    const int o = l >> 3;
    const int c = l & 7;

    const int* idxp = idx + (size_t)qi * 64;
    int rows[8];
#pragma unroll
    for (int i = 0; i < 8; ++i) rows[i] = idxp[i * 8 + o];

    const size_t hoff = (size_t)hp * 64 + c * 8;

    uint4 kd[8];
#pragma unroll
    for (int i = 0; i < 8; ++i)
        kd[i] = *(const uint4*)(k + srcbase + (size_t)rows[i] * 256 + hoff);
    uint4 qc = *(const uint4*)(q + (size_t)qi * 256 + hoff);

    float s[8];
#pragma unroll
    for (int i = 0; i < 8; ++i) {
        float si = 0.f;
        si = dot2f16(kd[i].x, qc.x, si);
        si = dot2f16(kd[i].y, qc.y, si);
        si = dot2f16(kd[i].z, qc.z, si);
        si = dot2f16(kd[i].w, qc.w, si);
        si += __shfl_xor(si, 1);
        si += __shfl_xor(si, 2);
        s[i] = si * 0.17677669529663687f;
    }

    uint4 vd[8];
#pragma unroll
    for (int i = 0; i < 8; ++i)
        vd[i] = *(const uint4*)(v + srcbase + (size_t)rows[i] * 256 + hoff);

    float mx = s[0];
#pragma unroll
    for (int i = 1; i < 8; ++i) mx = fmaxf(mx, s[i]);
    mx = fmaxf(mx, __shfl_xor(mx, 8));
    mx = fmaxf(mx, __shfl_xor(mx, 16));
    mx = fmaxf(mx, __shfl_xor(mx, 32));
    float p[8], sum = 0.f;
#pragma unroll
    for (int i = 0; i < 8; ++i) { p[i] = __expf(s[i] - mx); sum += p[i]; }
    sum += __shfl_xor(sum, 8);
    sum += __shfl_xor(sum, 16);
    sum += __shfl_xor(sum, 32);
    float inv = 1.f / sum;

    u32 A0 = 0, A1 = 0, A2 = 0, A3 = 0;
#pragma unroll
    for (int i = 0; i < 8; ++i) {
        float pi = p[i] * inv;
        u32 pp = pkrtz(pi, pi);
        A0 = pk_fma16(pp, vd[i].x, A0);
        A1 = pk_fma16(pp, vd[i].y, A1);
        A2 = pk_fma16(pp, vd[i].z, A2);
        A3 = pk_fma16(pp, vd[i].w, A3);
    }

    const bool ob0 = (o & 1) != 0;
    const bool ob1 = (o & 2) != 0;
    {
        u32 t0 = ob0 ? A0 : A2;
        u32 t1 = ob0 ? A1 : A3;
        t0 = __shfl_xor((int)t0, 8);
        t1 = __shfl_xor((int)t1, 8);
        A0 = pk_add16(ob0 ? A2 : A0, t0);
        A1 = pk_add16(ob0 ? A3 : A1, t1);
    }
    {
        u32 u0 = ob1 ? A0 : A1;
        u0 = __shfl_xor((int)u0, 16);
        A0 = pk_add16(ob1 ? A1 : A0, u0);
    }
    A0 = pk_add16(A0, (u32)__shfl_xor((int)A0, 32));

    if (o < 4) {
        int j = 2 * (o & 1) + ((o >> 1) & 1);
        f16x2 hv = __builtin_bit_cast(f16x2, A0);
        u32 packed = (u32)f2bf((float)hv.x) | ((u32)f2bf((float)hv.y) << 16);
        *(u32*)(msg + (size_t)qi * 256 + hp * 64 + c * 8 + j * 2) = packed;
    }
}

// ---------------------------------------------------------------------------
extern "C" void kernel_launch(void* const* d_in, const int* in_sizes, int n_in,
                              void* d_out, int out_size, void* d_ws, size_t ws_size,
                              hipStream_t stream)
{
    const float* x      = (const float*)d_in[0];
    const float* source = (const float*)d_in[1];
    const int*   eidx   = (const int*)d_in[2];
    const float* Wq     = (const float*)d_in[3];
    const float* Wk     = (const float*)d_in[4];
    const float* Wv     = (const float*)d_in[5];
    const float* Wm     = (const float*)d_in[6];
    const float* W1     = (const float*)d_in[7];
    const float* W2     = (const float*)d_in[8];
    const float* g1     = (const float*)d_in[9];
    const float* b1     = (const float*)d_in[10];
    const float* g2     = (const float*)d_in[11];
    const float* b2     = (const float*)d_in[12];
    float* out = (float*)d_out;

    char* ws = (char*)d_ws;
    const size_t SZB = (size_t)MROWS * 256 * 2;    // 4.9 MB
    u16* qb     = (u16*)(ws);                      // f16 q
    u16* kb     = (u16*)(ws + SZB);                // f16 k
    u16* vb     = (u16*)(ws + 2 * SZB);            // f16 v
    u16* msgb   = (u16*)(ws + 3 * SZB);            // bf16 attn output
    u16* hx     = (u16*)(ws + 4 * SZB);            // bf16 [9600][512] x@W1_top
    u16* h1b    = (u16*)(ws + 6 * SZB);            // bf16 [9600][512]
    u16* Wqkvh  = (u16*)(ws + 8 * SZB);            // f16 [1280][256]
    u16* Wmt    = Wqkvh + 1280 * 256;              // bf16 [256][256]
    u16* W1bt   = Wmt + 256 * 256;                 // bf16 [512][256]
    u16* W2t    = W1bt + 512 * 256;                // bf16 [256][512]

    dim3 blk(256);

    // weight transposes only
    prep_kernel<<<dim3(2560), blk, 0, stream>>>(Wq, Wk, Wv, Wm, W1, W2,
                                                Wqkvh, Wmt, W1bt, W2t);

    // q|k|v|h_top from fp32 inputs (f16 MFMA), N=1280, 1500 blocks
    qkvh_kernel<<<dim3(10, 150), blk, 0, stream>>>(x, source, Wqkvh, qb, hx);

    // gathered attention -> msg (bf16)
    attn_kernel<<<dim3(MROWS), blk, 0, stream>>>(qb, kb, vb, eidx, msgb);

    // Wm+LN1+W1_bot fused (msgln stays in LDS) -> h1b
    wm_w1_kernel<<<dim3(300), blk, 0, stream>>>(msgb, Wmt, W1bt, hx, g1, b1, h1b);

    // h1 @ W2 + LN2 + residual -> fp32 out
    gemm_ln_kernel<true, false><<<dim3(300), blk, 0, stream>>>(
        h1b, 512, W2t, 512, g2, b2, x, out, 512);
}

// Round 18
// 93.948 us; speedup vs baseline: 1.0490x; 1.0490x over previous
//
#include <hip/hip_runtime.h>
#include <hip/hip_bf16.h>

#define D_MODEL 256
#define LQ 4800
#define NB 2
#define MROWS (NB * LQ)       // 9600
#define LN_EPS 1e-5f

typedef unsigned int u32;
typedef unsigned short u16;
typedef unsigned char u8;
typedef __attribute__((ext_vector_type(8))) short bf16x8;
typedef __attribute__((ext_vector_type(4))) float f32x4;
typedef __attribute__((ext_vector_type(2))) float f32x2v;
typedef __attribute__((ext_vector_type(4))) u32 u32x4;
typedef __attribute__((ext_vector_type(2))) _Float16 f16x2;
typedef __attribute__((ext_vector_type(8))) _Float16 f16x8;

__device__ __forceinline__ u16 f2bf(float f) {
    __hip_bfloat16 h = __float2bfloat16(f);
    return *reinterpret_cast<u16*>(&h);
}
__device__ __forceinline__ float bf2f(u32 bits16) {
    return __uint_as_float(bits16 << 16);
}

// f16 pair dot into f32 (v_dot2_f32_f16)
__device__ __forceinline__ float dot2f16(u32 a, u32 b, float c) {
#if __has_builtin(__builtin_amdgcn_fdot2)
    return __builtin_amdgcn_fdot2(__builtin_bit_cast(f16x2, a),
                                  __builtin_bit_cast(f16x2, b), c, false);
#else
    f16x2 av = __builtin_bit_cast(f16x2, a), bv = __builtin_bit_cast(f16x2, b);
    c = fmaf((float)av.x, (float)bv.x, c);
    return fmaf((float)av.y, (float)bv.y, c);
#endif
}
__device__ __forceinline__ u32 pk_fma16(u32 a, u32 b, u32 c) {
    u32 d;
    asm("v_pk_fma_f16 %0, %1, %2, %3" : "=v"(d) : "v"(a), "v"(b), "v"(c));
    return d;
}
__device__ __forceinline__ u32 pk_add16(u32 a, u32 b) {
    u32 d;
    asm("v_pk_add_f16 %0, %1, %2" : "=v"(d) : "v"(a), "v"(b));
    return d;
}
__device__ __forceinline__ u32 pkrtz(float a, float b) {
    return __builtin_bit_cast(u32, __builtin_amdgcn_cvt_pkrtz(a, b));
}
__device__ __forceinline__ void gload_lds(const u16* src, u16* dst) {
    __builtin_amdgcn_global_load_lds(
        (const __attribute__((address_space(1))) u32*)src,
        (__attribute__((address_space(3))) u32*)dst, 16, 0, 0);
}
__device__ __forceinline__ void gload_lds_f32(const float* src, u32* dst) {
    __builtin_amdgcn_global_load_lds(
        (const __attribute__((address_space(1))) u32*)src,
        (__attribute__((address_space(3))) u32*)dst, 16, 0, 0);
}

// ---------------- fp8 e4m3 helpers (HW cvt when available) ----------------
__device__ __forceinline__ float fp8_to_f32_sw(u32 b) {
    u32 s = (b & 0x80) << 24;
    u32 e = (b >> 3) & 0xf;
    u32 m = b & 7;
    float mag = (e == 0) ? (float)m * 0.001953125f
                         : __uint_as_float(((e + 120) << 23) | (m << 20));
    return __uint_as_float(__float_as_uint(mag) | s);
}
__device__ __forceinline__ u32 f32_to_fp8_sw(float v) {
    u32 bits = __float_as_uint(v);
    u32 s = (bits >> 24) & 0x80;
    float a = fabsf(v);
    if (!(a >= 0.0009765625f)) return s;              // tiny/NaN-safe -> 0
    if (a >= 448.f) return s | 0x7e;
    if (a < 0.015625f) {
        u32 m = (u32)(a * 512.f + 0.5f);
        if (m > 7) m = 7;
        return s | m;
    }
    int e = ((bits >> 23) & 0xff) - 127;
    u32 mant = bits & 0x7fffff;
    u32 m3 = mant >> 20, rem = mant & 0xfffff;
    if (rem > 0x80000 || (rem == 0x80000 && (m3 & 1))) { m3++; if (m3 == 8) { m3 = 0; e++; } }
    if (e > 8) return s | 0x7e;
    return s | ((u32)(e + 7) << 3) | m3;
}
// 4 fp8 (one u32) -> two packed f16 pairs
__device__ __forceinline__ void fp8x4_to_2xf16(u32 v, u32& lo, u32& hi) {
#if __has_builtin(__builtin_amdgcn_cvt_pk_f32_fp8)
    f32x2v a = __builtin_amdgcn_cvt_pk_f32_fp8((int)v, false);
    f32x2v b = __builtin_amdgcn_cvt_pk_f32_fp8((int)v, true);
    lo = pkrtz(a[0], a[1]);
    hi = pkrtz(b[0], b[1]);
#else
    lo = pkrtz(fp8_to_f32_sw(v & 0xff), fp8_to_f32_sw((v >> 8) & 0xff));
    hi = pkrtz(fp8_to_f32_sw((v >> 16) & 0xff), fp8_to_f32_sw(v >> 24));
#endif
}
__device__ __forceinline__ u8 f32_to_fp8b(float v) {
#if __has_builtin(__builtin_amdgcn_cvt_pk_fp8_f32)
    return (u8)(__builtin_amdgcn_cvt_pk_fp8_f32(v, v, 0, false) & 0xff);
#else
    return (u8)f32_to_fp8_sw(v);
#endif
}

// ---------------------------------------------------------------------------
// Prep: weight transposes only. grid 2560.
//  [0,768)    Wq|Wk|Wv -> Wqkvh (f16) rows 0..767
//  [768,1024) Wm -> Wmt (bf16)
//  [1024,2048) W1: k<256 -> Wqkvh (f16) rows 768..1279; k>=256 -> W1bt bf16
//  [2048,2560) W2 -> W2t (bf16, ldt 512)
// ---------------------------------------------------------------------------
__global__ __launch_bounds__(256) void prep_kernel(
    const float* __restrict__ Wq, const float* __restrict__ Wk,
    const float* __restrict__ Wv, const float* __restrict__ Wm,
    const float* __restrict__ W1, const float* __restrict__ W2,
    u16* __restrict__ Wqkvh, u16* __restrict__ Wmt,
    u16* __restrict__ W1bt, u16* __restrict__ W2t)
{
    __shared__ float tile[16][17];
    const int t = threadIdx.x, tx = t & 15, ty = t >> 4;
    int sub = blockIdx.x;

    const float* W; int Nd, tn, tk, drow, dcol, ldt; u16* dst; bool f16o = false;
    if (sub < 768) {
        W = sub < 256 ? Wq : (sub < 512 ? Wk : Wv);
        int s = sub & 255; Nd = 256; tn = s % 16; tk = s / 16;
        dst = Wqkvh; drow = (sub >> 8) * 256 + tn * 16; dcol = tk * 16; ldt = 256; f16o = true;
    } else if (sub < 1024) {
        W = Wm; int s = sub - 768; Nd = 256; tn = s % 16; tk = s / 16;
        dst = Wmt; drow = tn * 16; dcol = tk * 16; ldt = 256;
    } else if (sub < 2048) {
        W = W1; int s = sub - 1024; Nd = 512; tn = s % 32; tk = s / 32;
        if (tk < 16) { dst = Wqkvh; drow = 768 + tn * 16; dcol = tk * 16; ldt = 256; f16o = true; }
        else         { dst = W1bt;  drow = tn * 16; dcol = (tk - 16) * 16; ldt = 256; }
    } else {
        W = W2; int s = sub - 2048; Nd = 256; tn = s % 16; tk = s / 16;
        dst = W2t; drow = tn * 16; dcol = tk * 16; ldt = 512;
    }
    tile[ty][tx] = W[(size_t)(tk * 16 + ty) * Nd + tn * 16 + tx];
    __syncthreads();
    float v = tile[tx][ty];
    u16 o;
    if (f16o) { _Float16 h = (_Float16)v; o = __builtin_bit_cast(u16, h); }
    else      o = f2bf(v);
    dst[(size_t)(drow + ty) * ldt + dcol + tx] = o;
}

// ---------------------------------------------------------------------------
// qkv+h_top GEMM: [q|k|v|h_top] = A_fp32 @ Wqkvh^T (f16 MFMA, K=256, N=1280).
// Epilogue: q -> f16; k,v -> fp8 e4m3 byte buffers; h_top -> bf16 hx.
// ---------------------------------------------------------------------------
__global__ __launch_bounds__(256) void qkvh_kernel(
    const float* __restrict__ x, const float* __restrict__ source,
    const u16* __restrict__ Wqkvh,
    u16* __restrict__ qb, u8* __restrict__ kb8, u8* __restrict__ vb8,
    u16* __restrict__ hx)
{
    __shared__ __align__(16) float As32[64 * 32];   // 8 KB
    __shared__ __align__(16) u16 Bs[128 * 32];      // 8 KB

    const int t = threadIdx.x, l = t & 63, w = t >> 6;
    const int m0 = blockIdx.y * 64, n0 = blockIdx.x * 128;
    const int wr = w >> 1, wc = w & 1;
    const float* Ap = (n0 < 256 || n0 >= 768) ? x : source;

    const int srow = l >> 2, sch = (l & 3) ^ (srow & 3);   // B staging
    const int arow8 = l >> 3, acw = (l & 7) ^ (arow8 & 7); // A staging (fp32)
    const int r = l & 15, ch = l >> 4;

    f32x4 acc[2][4];
#pragma unroll
    for (int i = 0; i < 2; ++i)
#pragma unroll
        for (int j = 0; j < 4; ++j) acc[i][j] = (f32x4){0.f, 0.f, 0.f, 0.f};

    for (int k0 = 0; k0 < 256; k0 += 32) {
#pragma unroll
        for (int h = 0; h < 2; ++h) {
            const float* asrc = Ap + (size_t)(m0 + w * 16 + h * 8 + arow8) * 256 + k0 + acw * 4;
            gload_lds_f32(asrc, (u32*)As32 + w * 512 + h * 256);
        }
#pragma unroll
        for (int g = 0; g < 2; ++g) {
            int grp = w * 2 + g;
            gload_lds(Wqkvh + (size_t)(n0 + grp * 16 + srow) * 256 + k0 + sch * 8,
                      Bs + grp * 512);
        }
        __syncthreads();

        f16x8 af[2];
#pragma unroll
        for (int i = 0; i < 2; ++i) {
            int ar = wr * 32 + i * 16 + r;
            int s0 = (2 * ch) ^ (ar & 7), s1 = (2 * ch + 1) ^ (ar & 7);
            f32x4 alo = *(const f32x4*)((const char*)As32 + ar * 128 + s0 * 16);
            f32x4 ahi = *(const f32x4*)((const char*)As32 + ar * 128 + s1 * 16);
            u32x4 pk = { pkrtz(alo.x, alo.y), pkrtz(alo.z, alo.w),
                         pkrtz(ahi.x, ahi.y), pkrtz(ahi.z, ahi.w) };
            af[i] = __builtin_bit_cast(f16x8, pk);
        }
#pragma unroll
        for (int j = 0; j < 4; ++j) {
            int br = wc * 64 + j * 16 + r;
            f16x8 bf = *(const f16x8*)((const char*)Bs + br * 64 + ((ch ^ (r & 3)) * 16));
#pragma unroll
            for (int i = 0; i < 2; ++i)
                acc[i][j] = __builtin_amdgcn_mfma_f32_16x16x32_f16(af[i], bf, acc[i][j], 0, 0, 0);
        }
        __syncthreads();
    }

    const int q4 = l >> 4;
#pragma unroll
    for (int i = 0; i < 2; ++i)
#pragma unroll
        for (int j = 0; j < 4; ++j) {
            int col = n0 + wc * 64 + j * 16 + r;
#pragma unroll
            for (int reg = 0; reg < 4; ++reg) {
                int row = m0 + wr * 32 + i * 16 + q4 * 4 + reg;
                float vv = acc[i][j][reg];
                if (col < 256) {
                    _Float16 hv = (_Float16)vv;
                    qb[(size_t)row * 256 + col] = __builtin_bit_cast(u16, hv);
                } else if (col < 512) {
                    kb8[(size_t)row * 256 + (col - 256)] = f32_to_fp8b(vv);
                } else if (col < 768) {
                    vb8[(size_t)row * 256 + (col - 512)] = f32_to_fp8b(vv);
                } else {
                    hx[(size_t)row * 512 + (col - 768)] = f2bf(vv);
                }
            }
        }
}

// ---------------------------------------------------------------------------
// Fused Wm+LN1+W1_bot (unchanged structure, best-measured r16 base).
// ---------------------------------------------------------------------------
__global__ __launch_bounds__(256) void wm_w1_kernel(
    const u16* __restrict__ msg, const u16* __restrict__ Wmt,
    const u16* __restrict__ W1bt, const u16* __restrict__ hx,
    const float* __restrict__ g1, const float* __restrict__ b1,
    u16* __restrict__ h1b)
{
    __shared__ __align__(16) u16 As[32 * 32];
    __shared__ __align__(16) u16 Bs[512 * 32];
    __shared__ __align__(16) u16 mln[32 * 256];
    __shared__ float2 red[32][2];

    const int t = threadIdx.x, l = t & 63, w = t >> 6;
    const int m0 = blockIdx.x * 32;
    const int srow = l >> 2, sch = (l & 3) ^ (srow & 3);
    const int r = l & 15, ch = l >> 4, q4 = l >> 4;

    {   // Phase A
        const int wr = w >> 1, wc = w & 1;
        f32x4 acc[8];
#pragma unroll
        for (int j = 0; j < 8; ++j) acc[j] = (f32x4){0.f, 0.f, 0.f, 0.f};

        for (int k0 = 0; k0 < 256; k0 += 32) {
            if (w < 2)
                gload_lds(msg + (size_t)(m0 + w * 16 + srow) * 256 + k0 + sch * 8, As + w * 512);
#pragma unroll
            for (int g = 0; g < 4; ++g) {
                int grp = w * 4 + g;
                gload_lds(Wmt + (size_t)(grp * 16 + srow) * 256 + k0 + sch * 8, Bs + grp * 512);
            }
            __syncthreads();
            bf16x8 af = *(const bf16x8*)((const char*)As + (wr * 16 + r) * 64 + ((ch ^ (r & 3)) * 16));
#pragma unroll
            for (int j = 0; j < 8; ++j) {
                int br = wc * 128 + j * 16 + r;
                bf16x8 bf = *(const bf16x8*)((const char*)Bs + br * 64 + ((ch ^ (r & 3)) * 16));
                acc[j] = __builtin_amdgcn_mfma_f32_16x16x32_bf16(af, bf, acc[j], 0, 0, 0);
            }
            __syncthreads();
        }

        float rs[4], rq[4];
#pragma unroll
        for (int reg = 0; reg < 4; ++reg) {
            float s = 0.f, sq = 0.f;
#pragma unroll
            for (int j = 0; j < 8; ++j) { float vv = acc[j][reg]; s += vv; sq += vv * vv; }
            rs[reg] = s; rq[reg] = sq;
        }
#pragma unroll
        for (int off = 1; off <= 8; off <<= 1)
#pragma unroll
            for (int reg = 0; reg < 4; ++reg) {
                rs[reg] += __shfl_xor(rs[reg], off);
                rq[reg] += __shfl_xor(rq[reg], off);
            }
        if (r == 0)
#pragma unroll
            for (int reg = 0; reg < 4; ++reg)
                red[wr * 16 + q4 * 4 + reg][wc] = make_float2(rs[reg], rq[reg]);
        __syncthreads();

#pragma unroll
        for (int reg = 0; reg < 4; ++reg) {
            int row = wr * 16 + q4 * 4 + reg;
            float sum = red[row][0].x + red[row][1].x;
            float sq  = red[row][0].y + red[row][1].y;
            float mu  = sum * 0.00390625f;
            float var = sq * 0.00390625f - mu * mu;
            float rstd = rsqrtf(var + LN_EPS);
#pragma unroll
            for (int j = 0; j < 8; ++j) {
                int col = wc * 128 + j * 16 + r;
                float vv = (acc[j][reg] - mu) * rstd * g1[col] + b1[col];
                int cc = col >> 3, slot = cc ^ (row & 7);
                *(u16*)((char*)mln + row * 512 + slot * 16 + (col & 7) * 2) = f2bf(vv);
            }
        }
        __syncthreads();
    }

    {   // Phase B
        f32x4 acc2[2][8];
#pragma unroll
        for (int i = 0; i < 2; ++i)
#pragma unroll
            for (int j = 0; j < 8; ++j) acc2[i][j] = (f32x4){0.f, 0.f, 0.f, 0.f};

        for (int k0 = 0; k0 < 256; k0 += 32) {
#pragma unroll
            for (int g = 0; g < 8; ++g) {
                int row = w * 128 + g * 16 + srow;
                gload_lds(W1bt + (size_t)row * 256 + k0 + sch * 8, Bs + (w * 8 + g) * 512);
            }
            __syncthreads();
            bf16x8 af2[2];
#pragma unroll
            for (int i = 0; i < 2; ++i) {
                int ar = i * 16 + r;
                int c0 = (k0 >> 3) + ch;
                af2[i] = *(const bf16x8*)((const char*)mln + ar * 512 + ((c0 ^ (ar & 7)) * 16));
            }
#pragma unroll
            for (int j = 0; j < 8; ++j) {
                int br = w * 128 + j * 16 + r;
                bf16x8 bf = *(const bf16x8*)((const char*)Bs + br * 64 + ((ch ^ (r & 3)) * 16));
#pragma unroll
                for (int i = 0; i < 2; ++i)
                    acc2[i][j] = __builtin_amdgcn_mfma_f32_16x16x32_bf16(af2[i], bf, acc2[i][j], 0, 0, 0);
            }
            __syncthreads();
        }

#pragma unroll
        for (int i = 0; i < 2; ++i)
#pragma unroll
            for (int j = 0; j < 8; ++j) {
                int col = w * 128 + j * 16 + r;
#pragma unroll
                for (int reg = 0; reg < 4; ++reg) {
                    int row = i * 16 + q4 * 4 + reg;
                    size_t oidx = (size_t)(m0 + row) * 512 + col;
                    float vv = acc2[i][j][reg] + bf2f((u32)hx[oidx]);
                    vv = fmaxf(vv, 0.f);
                    h1b[oidx] = f2bf(vv);
                }
            }
    }
}

// ---------------------------------------------------------------------------
// GEMM (32 rows, N=256) + fused LayerNorm epilogue (W2+LN2+residual).
// ---------------------------------------------------------------------------
template<bool RESID, bool OUT_BF16>
__global__ __launch_bounds__(256) void gemm_ln_kernel(
    const u16* __restrict__ A, int lda,
    const u16* __restrict__ Bt, int ldb,
    const float* __restrict__ g, const float* __restrict__ b,
    const float* __restrict__ xres,
    void* __restrict__ Cout, int K)
{
    __shared__ __align__(16) u16 As[32 * 32];
    __shared__ __align__(16) u16 Bs[256 * 32];
    __shared__ float2 red[32][2];

    const int t  = threadIdx.x, l = t & 63, w = t >> 6;
    const int m0 = blockIdx.x * 32;
    const int wr = w >> 1, wc = w & 1;
    const int srow = l >> 2, sch = (l & 3) ^ (srow & 3);
    const int r = l & 15, ch = l >> 4, q4 = l >> 4;

    f32x4 acc[8];
#pragma unroll
    for (int j = 0; j < 8; ++j) acc[j] = (f32x4){0.f, 0.f, 0.f, 0.f};

    for (int k0 = 0; k0 < K; k0 += 32) {
        if (w < 2)
            gload_lds(A + (size_t)(m0 + w * 16 + srow) * lda + k0 + sch * 8, As + w * 512);
#pragma unroll
        for (int gg = 0; gg < 4; ++gg) {
            int grp = w * 4 + gg;
            gload_lds(Bt + (size_t)(grp * 16 + srow) * ldb + k0 + sch * 8, Bs + grp * 512);
        }
        __syncthreads();
        bf16x8 af = *(const bf16x8*)((const char*)As + (wr * 16 + r) * 64 + ((ch ^ (r & 3)) * 16));
#pragma unroll
        for (int j = 0; j < 8; ++j) {
            int br = wc * 128 + j * 16 + r;
            bf16x8 bf = *(const bf16x8*)((const char*)Bs + br * 64 + ((ch ^ (r & 3)) * 16));
            acc[j] = __builtin_amdgcn_mfma_f32_16x16x32_bf16(af, bf, acc[j], 0, 0, 0);
        }
        __syncthreads();
    }

    float rs[4], rq[4];
#pragma unroll
    for (int reg = 0; reg < 4; ++reg) {
        float s = 0.f, sq = 0.f;
#pragma unroll
        for (int j = 0; j < 8; ++j) { float vv = acc[j][reg]; s += vv; sq += vv * vv; }
        rs[reg] = s; rq[reg] = sq;
    }
#pragma unroll
    for (int off = 1; off <= 8; off <<= 1)
#pragma unroll
        for (int reg = 0; reg < 4; ++reg) {
            rs[reg] += __shfl_xor(rs[reg], off);
            rq[reg] += __shfl_xor(rq[reg], off);
        }
    if (r == 0)
#pragma unroll
        for (int reg = 0; reg < 4; ++reg)
            red[wr * 16 + q4 * 4 + reg][wc] = make_float2(rs[reg], rq[reg]);
    __syncthreads();

    float gj[8], bj[8];
#pragma unroll
    for (int j = 0; j < 8; ++j) {
        int col = wc * 128 + j * 16 + r;
        gj[j] = g[col]; bj[j] = b[col];
    }

#pragma unroll
    for (int reg = 0; reg < 4; ++reg) {
        int row = wr * 16 + q4 * 4 + reg;
        float sum = red[row][0].x + red[row][1].x;
        float sq  = red[row][0].y + red[row][1].y;
        float mu  = sum * 0.00390625f;
        float var = sq * 0.00390625f - mu * mu;
        float rstd = rsqrtf(var + LN_EPS);
#pragma unroll
        for (int j = 0; j < 8; ++j) {
            int col = wc * 128 + j * 16 + r;
            float vv = (acc[j][reg] - mu) * rstd * gj[j] + bj[j];
            size_t oidx = (size_t)(m0 + row) * 256 + col;
            if (RESID) vv += xres[oidx];
            if (OUT_BF16) ((u16*)Cout)[oidx] = f2bf(vv);
            else          ((float*)Cout)[oidx] = vv;
        }
    }
}

// ---------------------------------------------------------------------------
// Gathered attention, fp8 K/V: rows are 256B (vs 512B f16) -> gather cache-
// line count per query halves (256 -> 128 lines). q stays f16 (broadcast).
// wave = (query, head-pair); o = l>>3 key-set, c = l&7 8B chunk of the 64B
// two-head fp8 slice. Decode fp8->f16 in-register, dot2/pk_fma16 as before.
// XCD batch-affinity relabel.
// ---------------------------------------------------------------------------
__global__ __launch_bounds__(256, 8) void attn_kernel(
    const u16* __restrict__ q, const u8* __restrict__ k8,
    const u8* __restrict__ v8, const int* __restrict__ idx,
    u16* __restrict__ msg)
{
    const int t  = threadIdx.x;
    const int l  = t & 63;
    const int hp = t >> 6;
    const int bid = blockIdx.x;
    const int x8 = bid & 7, jj = bid >> 3;
    const int qi = (x8 < 4) ? (x8 * 1200 + jj) : (LQ + (x8 - 4) * 1200 + jj);
    const int n  = qi / LQ;
    const size_t srcbase8 = (size_t)n * LQ * 256;   // bytes

    const int o = l >> 3;
    const int c = l & 7;

    const int* idxp = idx + (size_t)qi * 64;
    int rows[8];
#pragma unroll
    for (int i = 0; i < 8; ++i) rows[i] = idxp[i * 8 + o];

    const size_t hoff8 = (size_t)hp * 64 + c * 8;       // bytes within row
    const size_t hoffq = (size_t)hp * 64 + c * 8;       // u16 units in q row

    // ---- K phase (fp8, 8B/lane) ----
    uint2 kd[8];
#pragma unroll
    for (int i = 0; i < 8; ++i)
        kd[i] = *(const uint2*)(k8 + srcbase8 + (size_t)rows[i] * 256 + hoff8);
    uint4 qc = *(const uint4*)(q + (size_t)qi * 256 + hoffq);

    float s[8];
#pragma unroll
    for (int i = 0; i < 8; ++i) {
        u32 k0l, k0h, k1l, k1h;
        fp8x4_to_2xf16(kd[i].x, k0l, k0h);
        fp8x4_to_2xf16(kd[i].y, k1l, k1h);
        float si = 0.f;
        si = dot2f16(k0l, qc.x, si);
        si = dot2f16(k0h, qc.y, si);
        si = dot2f16(k1l, qc.z, si);
        si = dot2f16(k1h, qc.w, si);
        si += __shfl_xor(si, 1);
        si += __shfl_xor(si, 2);
        s[i] = si * 0.17677669529663687f;
    }

    // ---- V phase (fp8): latency hides under softmax ----
    uint2 vd[8];
#pragma unroll
    for (int i = 0; i < 8; ++i)
        vd[i] = *(const uint2*)(v8 + srcbase8 + (size_t)rows[i] * 256 + hoff8);

    // ---- softmax over 64 keys ----
    float mx = s[0];
#pragma unroll
    for (int i = 1; i < 8; ++i) mx = fmaxf(mx, s[i]);
    mx = fmaxf(mx, __shfl_xor(mx, 8));
    mx = fmaxf(mx, __shfl_xor(mx, 16));
    mx = fmaxf(mx, __shfl_xor(mx, 32));
    float p[8], sum = 0.f;
#pragma unroll
    for (int i = 0; i < 8; ++i) { p[i] = __expf(s[i] - mx); sum += p[i]; }
    sum += __shfl_xor(sum, 8);
    sum += __shfl_xor(sum, 16);
    sum += __shfl_xor(sum, 32);
    float inv = 1.f / sum;

    // ---- PV: decode V, f16 packed fma ----
    u32 A0 = 0, A1 = 0, A2 = 0, A3 = 0;
#pragma unroll
    for (int i = 0; i < 8; ++i) {
        float pi = p[i] * inv;
        u32 pp = pkrtz(pi, pi);
        u32 v0l, v0h, v1l, v1h;
        fp8x4_to_2xf16(vd[i].x, v0l, v0h);
        fp8x4_to_2xf16(vd[i].y, v1l, v1h);
        A0 = pk_fma16(pp, v0l, A0);
        A1 = pk_fma16(pp, v0h, A1);
        A2 = pk_fma16(pp, v1l, A2);
        A3 = pk_fma16(pp, v1h, A3);
    }

    // ---- split-reduce over the 8 o-sets ----
    const bool ob0 = (o & 1) != 0;
    const bool ob1 = (o & 2) != 0;
    {
        u32 t0 = ob0 ? A0 : A2;
        u32 t1 = ob0 ? A1 : A3;
        t0 = __shfl_xor((int)t0, 8);
        t1 = __shfl_xor((int)t1, 8);
        A0 = pk_add16(ob0 ? A2 : A0, t0);
        A1 = pk_add16(ob0 ? A3 : A1, t1);
    }
    {
        u32 u0 = ob1 ? A0 : A1;
        u0 = __shfl_xor((int)u0, 16);
        A0 = pk_add16(ob1 ? A1 : A0, u0);
    }
    A0 = pk_add16(A0, (u32)__shfl_xor((int)A0, 32));

    if (o < 4) {
        int j = 2 * (o & 1) + ((o >> 1) & 1);
        f16x2 hv = __builtin_bit_cast(f16x2, A0);
        u32 packed = (u32)f2bf((float)hv.x) | ((u32)f2bf((float)hv.y) << 16);
        *(u32*)(msg + (size_t)qi * 256 + hp * 64 + c * 8 + j * 2) = packed;
    }
}

// ---------------------------------------------------------------------------
extern "C" void kernel_launch(void* const* d_in, const int* in_sizes, int n_in,
                              void* d_out, int out_size, void* d_ws, size_t ws_size,
                              hipStream_t stream)
{
    const float* x      = (const float*)d_in[0];
    const float* source = (const float*)d_in[1];
    const int*   eidx   = (const int*)d_in[2];
    const float* Wq     = (const float*)d_in[3];
    const float* Wk     = (const float*)d_in[4];
    const float* Wv     = (const float*)d_in[5];
    const float* Wm     = (const float*)d_in[6];
    const float* W1     = (const float*)d_in[7];
    const float* W2     = (const float*)d_in[8];
    const float* g1     = (const float*)d_in[9];
    const float* b1     = (const float*)d_in[10];
    const float* g2     = (const float*)d_in[11];
    const float* b2     = (const float*)d_in[12];
    float* out = (float*)d_out;

    char* ws = (char*)d_ws;
    const size_t SZB = (size_t)MROWS * 256 * 2;    // 4.9 MB
    u16* qb     = (u16*)(ws);                      // f16 [9600][256]
    u8*  kb8    = (u8*)(ws + SZB);                 // fp8 [9600][256]
    u8*  vb8    = (u8*)(ws + SZB + SZB / 2);       // fp8 [9600][256]
    u16* msgb   = (u16*)(ws + 2 * SZB);            // bf16 attn output
    u16* hx     = (u16*)(ws + 3 * SZB);            // bf16 [9600][512] x@W1_top
    u16* h1b    = (u16*)(ws + 5 * SZB);            // bf16 [9600][512]
    u16* Wqkvh  = (u16*)(ws + 7 * SZB);            // f16 [1280][256]
    u16* Wmt    = Wqkvh + 1280 * 256;              // bf16 [256][256]
    u16* W1bt   = Wmt + 256 * 256;                 // bf16 [512][256]
    u16* W2t    = W1bt + 512 * 256;                // bf16 [256][512]

    dim3 blk(256);

    // weight transposes only
    prep_kernel<<<dim3(2560), blk, 0, stream>>>(Wq, Wk, Wv, Wm, W1, W2,
                                                Wqkvh, Wmt, W1bt, W2t);

    // q|k|v|h_top from fp32 inputs (f16 MFMA), k/v quantized to fp8
    qkvh_kernel<<<dim3(10, 150), blk, 0, stream>>>(x, source, Wqkvh, qb, kb8, vb8, hx);

    // gathered attention (fp8 K/V) -> msg (bf16)
    attn_kernel<<<dim3(MROWS), blk, 0, stream>>>(qb, kb8, vb8, eidx, msgb);

    // Wm+LN1+W1_bot fused (msgln stays in LDS) -> h1b
    wm_w1_kernel<<<dim3(300), blk, 0, stream>>>(msgb, Wmt, W1bt, hx, g1, b1, h1b);

    // h1 @ W2 + LN2 + residual -> fp32 out
    gemm_ln_kernel<true, false><<<dim3(300), blk, 0, stream>>>(
        h1b, 512, W2t, 512, g2, b2, x, out, 512);
}

// Round 19
// 92.568 us; speedup vs baseline: 1.0646x; 1.0149x over previous
//
#include <hip/hip_runtime.h>
#include <hip/hip_bf16.h>

#define D_MODEL 256
#define LQ 4800
#define NB 2
#define MROWS (NB * LQ)       // 9600
#define LN_EPS 1e-5f

typedef unsigned int u32;
typedef unsigned short u16;
typedef unsigned char u8;
typedef __attribute__((ext_vector_type(8))) short bf16x8;
typedef __attribute__((ext_vector_type(4))) float f32x4;
typedef __attribute__((ext_vector_type(2))) float f32x2v;
typedef __attribute__((ext_vector_type(4))) u32 u32x4;
typedef __attribute__((ext_vector_type(2))) _Float16 f16x2;
typedef __attribute__((ext_vector_type(8))) _Float16 f16x8;

__device__ __forceinline__ u16 f2bf(float f) {
    __hip_bfloat16 h = __float2bfloat16(f);
    return *reinterpret_cast<u16*>(&h);
}
__device__ __forceinline__ float bf2f(u32 bits16) {
    return __uint_as_float(bits16 << 16);
}
__device__ __forceinline__ u16 f2h(float f) {
    _Float16 h = (_Float16)f;
    return __builtin_bit_cast(u16, h);
}

// f16 pair dot into f32 (v_dot2_f32_f16)
__device__ __forceinline__ float dot2f16(u32 a, u32 b, float c) {
#if __has_builtin(__builtin_amdgcn_fdot2)
    return __builtin_amdgcn_fdot2(__builtin_bit_cast(f16x2, a),
                                  __builtin_bit_cast(f16x2, b), c, false);
#else
    f16x2 av = __builtin_bit_cast(f16x2, a), bv = __builtin_bit_cast(f16x2, b);
    c = fmaf((float)av.x, (float)bv.x, c);
    return fmaf((float)av.y, (float)bv.y, c);
#endif
}
__device__ __forceinline__ u32 pk_fma16(u32 a, u32 b, u32 c) {
    u32 d;
    asm("v_pk_fma_f16 %0, %1, %2, %3" : "=v"(d) : "v"(a), "v"(b), "v"(c));
    return d;
}
__device__ __forceinline__ u32 pk_add16(u32 a, u32 b) {
    u32 d;
    asm("v_pk_add_f16 %0, %1, %2" : "=v"(d) : "v"(a), "v"(b));
    return d;
}
__device__ __forceinline__ u32 pkrtz(float a, float b) {
    return __builtin_bit_cast(u32, __builtin_amdgcn_cvt_pkrtz(a, b));
}
__device__ __forceinline__ void gload_lds(const u16* src, u16* dst) {
    __builtin_amdgcn_global_load_lds(
        (const __attribute__((address_space(1))) u32*)src,
        (__attribute__((address_space(3))) u32*)dst, 16, 0, 0);
}

// ---------------- fp8 e4m3 helpers (HW cvt when available) ----------------
__device__ __forceinline__ float fp8_to_f32_sw(u32 b) {
    u32 s = (b & 0x80) << 24;
    u32 e = (b >> 3) & 0xf;
    u32 m = b & 7;
    float mag = (e == 0) ? (float)m * 0.001953125f
                         : __uint_as_float(((e + 120) << 23) | (m << 20));
    return __uint_as_float(__float_as_uint(mag) | s);
}
__device__ __forceinline__ u32 f32_to_fp8_sw(float v) {
    u32 bits = __float_as_uint(v);
    u32 s = (bits >> 24) & 0x80;
    float a = fabsf(v);
    if (!(a >= 0.0009765625f)) return s;
    if (a >= 448.f) return s | 0x7e;
    if (a < 0.015625f) {
        u32 m = (u32)(a * 512.f + 0.5f);
        if (m > 7) m = 7;
        return s | m;
    }
    int e = ((bits >> 23) & 0xff) - 127;
    u32 mant = bits & 0x7fffff;
    u32 m3 = mant >> 20, rem = mant & 0xfffff;
    if (rem > 0x80000 || (rem == 0x80000 && (m3 & 1))) { m3++; if (m3 == 8) { m3 = 0; e++; } }
    if (e > 8) return s | 0x7e;
    return s | ((u32)(e + 7) << 3) | m3;
}
__device__ __forceinline__ void fp8x4_to_2xf16(u32 v, u32& lo, u32& hi) {
#if __has_builtin(__builtin_amdgcn_cvt_pk_f32_fp8)
    f32x2v a = __builtin_amdgcn_cvt_pk_f32_fp8((int)v, false);
    f32x2v b = __builtin_amdgcn_cvt_pk_f32_fp8((int)v, true);
    lo = pkrtz(a[0], a[1]);
    hi = pkrtz(b[0], b[1]);
#else
    lo = pkrtz(fp8_to_f32_sw(v & 0xff), fp8_to_f32_sw((v >> 8) & 0xff));
    hi = pkrtz(fp8_to_f32_sw((v >> 16) & 0xff), fp8_to_f32_sw(v >> 24));
#endif
}
__device__ __forceinline__ u8 f32_to_fp8b(float v) {
#if __has_builtin(__builtin_amdgcn_cvt_pk_fp8_f32)
    return (u8)(__builtin_amdgcn_cvt_pk_fp8_f32(v, v, 0, false) & 0xff);
#else
    return (u8)f32_to_fp8_sw(v);
#endif
}

// ---------------------------------------------------------------------------
// Prep: input casts + weight transposes. grid 7360.
//  [0,2400)    x -> xh (f16)
//  [2400,4800) source -> sh (f16)
//  [4800,5568) Wq|Wk|Wv -> Wqkvh (f16) rows 0..767
//  [5568,5824) Wm -> Wmt (bf16)
//  [5824,6848) W1: k<256 -> Wqkvh rows 768..1279 (f16); k>=256 -> W1bt (bf16)
//  [6848,7360) W2 -> W2t (bf16, ldt 512)
// ---------------------------------------------------------------------------
__global__ __launch_bounds__(256) void prep_kernel(
    const float* __restrict__ x, const float* __restrict__ source,
    const float* __restrict__ Wq, const float* __restrict__ Wk,
    const float* __restrict__ Wv, const float* __restrict__ Wm,
    const float* __restrict__ W1, const float* __restrict__ W2,
    u16* __restrict__ xh, u16* __restrict__ sh,
    u16* __restrict__ Wqkvh, u16* __restrict__ Wmt,
    u16* __restrict__ W1bt, u16* __restrict__ W2t)
{
    __shared__ float tile[16][17];
    const int t = threadIdx.x, tx = t & 15, ty = t >> 4;
    int bid = blockIdx.x;

    if (bid < 4800) {
        const float* src = bid < 2400 ? x : source;
        u16* dst = bid < 2400 ? xh : sh;
        int b = bid < 2400 ? bid : bid - 2400;
        int i = (b * 256 + t) * 4;
        float4 v = *reinterpret_cast<const float4*>(src + i);
        ushort4 o;
        o.x = f2h(v.x); o.y = f2h(v.y); o.z = f2h(v.z); o.w = f2h(v.w);
        *reinterpret_cast<ushort4*>(dst + i) = o;
        return;
    }
    int sub = bid - 4800;
    const float* W; int Nd, tn, tk, drow, dcol, ldt; u16* dst; bool f16o = false;
    if (sub < 768) {
        W = sub < 256 ? Wq : (sub < 512 ? Wk : Wv);
        int s = sub & 255; Nd = 256; tn = s % 16; tk = s / 16;
        dst = Wqkvh; drow = (sub >> 8) * 256 + tn * 16; dcol = tk * 16; ldt = 256; f16o = true;
    } else if (sub < 1024) {
        W = Wm; int s = sub - 768; Nd = 256; tn = s % 16; tk = s / 16;
        dst = Wmt; drow = tn * 16; dcol = tk * 16; ldt = 256;
    } else if (sub < 2048) {
        W = W1; int s = sub - 1024; Nd = 512; tn = s % 32; tk = s / 32;
        if (tk < 16) { dst = Wqkvh; drow = 768 + tn * 16; dcol = tk * 16; ldt = 256; f16o = true; }
        else         { dst = W1bt;  drow = tn * 16; dcol = (tk - 16) * 16; ldt = 256; }
    } else {
        W = W2; int s = sub - 2048; Nd = 256; tn = s % 16; tk = s / 16;
        dst = W2t; drow = tn * 16; dcol = tk * 16; ldt = 512;
    }
    tile[ty][tx] = W[(size_t)(tk * 16 + ty) * Nd + tn * 16 + tx];
    __syncthreads();
    float v = tile[tx][ty];
    dst[(size_t)(drow + ty) * ldt + dcol + tx] = f16o ? f2h(v) : f2bf(v);
}

// ---------------------------------------------------------------------------
// qkv+h_top GEMM: [q|k|v|h_top] = A_f16 @ Wqkvh^T (f16 MFMA, K=256, N=1280).
// BM=64 x BN=256, 2x2 waves, FI=2, FJ=8 (16 MFMA per wave per K-step vs 5
// staging ops). A select by n0: x for {0,768,1024}, source for {256,512}.
// Epilogue: q -> f16; k,v -> fp8 e4m3; h_top -> bf16 hx.
// ---------------------------------------------------------------------------
__global__ __launch_bounds__(256) void qkvh_kernel(
    const u16* __restrict__ xh, const u16* __restrict__ sh,
    const u16* __restrict__ Wqkvh,
    u16* __restrict__ qb, u8* __restrict__ kb8, u8* __restrict__ vb8,
    u16* __restrict__ hx)
{
    __shared__ __align__(16) u16 As[64 * 32];    // 4 KB
    __shared__ __align__(16) u16 Bs[256 * 32];   // 16 KB

    const int t = threadIdx.x, l = t & 63, w = t >> 6;
    const int m0 = blockIdx.y * 64, n0 = blockIdx.x * 256;
    const int wr = w >> 1, wc = w & 1;
    const u16* Ap = (n0 == 256 || n0 == 512) ? sh : xh;

    const int srow = l >> 2, sch = (l & 3) ^ (srow & 3);
    const int r = l & 15, ch = l >> 4;

    f32x4 acc[2][8];
#pragma unroll
    for (int i = 0; i < 2; ++i)
#pragma unroll
        for (int j = 0; j < 8; ++j) acc[i][j] = (f32x4){0.f, 0.f, 0.f, 0.f};

    for (int k0 = 0; k0 < 256; k0 += 32) {
        // A: 4 groups of 16 rows, 1 per wave
        gload_lds(Ap + (size_t)(m0 + w * 16 + srow) * 256 + k0 + sch * 8, As + w * 512);
        // B: 16 groups, 4 per wave
#pragma unroll
        for (int g = 0; g < 4; ++g) {
            int grp = w * 4 + g;
            gload_lds(Wqkvh + (size_t)(n0 + grp * 16 + srow) * 256 + k0 + sch * 8,
                      Bs + grp * 512);
        }
        __syncthreads();

        f16x8 af[2];
#pragma unroll
        for (int i = 0; i < 2; ++i) {
            int ar = wr * 32 + i * 16 + r;
            af[i] = *(const f16x8*)((const char*)As + ar * 64 + ((ch ^ (r & 3)) * 16));
        }
#pragma unroll
        for (int j = 0; j < 8; ++j) {
            int br = wc * 128 + j * 16 + r;
            f16x8 bf = *(const f16x8*)((const char*)Bs + br * 64 + ((ch ^ (r & 3)) * 16));
#pragma unroll
            for (int i = 0; i < 2; ++i)
                acc[i][j] = __builtin_amdgcn_mfma_f32_16x16x32_f16(af[i], bf, acc[i][j], 0, 0, 0);
        }
        __syncthreads();
    }

    const int q4 = l >> 4;
#pragma unroll
    for (int i = 0; i < 2; ++i)
#pragma unroll
        for (int j = 0; j < 8; ++j) {
            int col = n0 + wc * 128 + j * 16 + r;
#pragma unroll
            for (int reg = 0; reg < 4; ++reg) {
                int row = m0 + wr * 32 + i * 16 + q4 * 4 + reg;
                float vv = acc[i][j][reg];
                if (col < 256) {
                    qb[(size_t)row * 256 + col] = f2h(vv);
                } else if (col < 512) {
                    kb8[(size_t)row * 256 + (col - 256)] = f32_to_fp8b(vv);
                } else if (col < 768) {
                    vb8[(size_t)row * 256 + (col - 512)] = f32_to_fp8b(vv);
                } else {
                    hx[(size_t)row * 512 + (col - 768)] = f2bf(vv);
                }
            }
        }
}

// ---------------------------------------------------------------------------
// Fused Wm+LN1+W1_bot (unchanged, best-measured base).
// ---------------------------------------------------------------------------
__global__ __launch_bounds__(256) void wm_w1_kernel(
    const u16* __restrict__ msg, const u16* __restrict__ Wmt,
    const u16* __restrict__ W1bt, const u16* __restrict__ hx,
    const float* __restrict__ g1, const float* __restrict__ b1,
    u16* __restrict__ h1b)
{
    __shared__ __align__(16) u16 As[32 * 32];
    __shared__ __align__(16) u16 Bs[512 * 32];
    __shared__ __align__(16) u16 mln[32 * 256];
    __shared__ float2 red[32][2];

    const int t = threadIdx.x, l = t & 63, w = t >> 6;
    const int m0 = blockIdx.x * 32;
    const int srow = l >> 2, sch = (l & 3) ^ (srow & 3);
    const int r = l & 15, ch = l >> 4, q4 = l >> 4;

    {   // Phase A
        const int wr = w >> 1, wc = w & 1;
        f32x4 acc[8];
#pragma unroll
        for (int j = 0; j < 8; ++j) acc[j] = (f32x4){0.f, 0.f, 0.f, 0.f};

        for (int k0 = 0; k0 < 256; k0 += 32) {
            if (w < 2)
                gload_lds(msg + (size_t)(m0 + w * 16 + srow) * 256 + k0 + sch * 8, As + w * 512);
#pragma unroll
            for (int g = 0; g < 4; ++g) {
                int grp = w * 4 + g;
                gload_lds(Wmt + (size_t)(grp * 16 + srow) * 256 + k0 + sch * 8, Bs + grp * 512);
            }
            __syncthreads();
            bf16x8 af = *(const bf16x8*)((const char*)As + (wr * 16 + r) * 64 + ((ch ^ (r & 3)) * 16));
#pragma unroll
            for (int j = 0; j < 8; ++j) {
                int br = wc * 128 + j * 16 + r;
                bf16x8 bf = *(const bf16x8*)((const char*)Bs + br * 64 + ((ch ^ (r & 3)) * 16));
                acc[j] = __builtin_amdgcn_mfma_f32_16x16x32_bf16(af, bf, acc[j], 0, 0, 0);
            }
            __syncthreads();
        }

        float rs[4], rq[4];
#pragma unroll
        for (int reg = 0; reg < 4; ++reg) {
            float s = 0.f, sq = 0.f;
#pragma unroll
            for (int j = 0; j < 8; ++j) { float vv = acc[j][reg]; s += vv; sq += vv * vv; }
            rs[reg] = s; rq[reg] = sq;
        }
#pragma unroll
        for (int off = 1; off <= 8; off <<= 1)
#pragma unroll
            for (int reg = 0; reg < 4; ++reg) {
                rs[reg] += __shfl_xor(rs[reg], off);
                rq[reg] += __shfl_xor(rq[reg], off);
            }
        if (r == 0)
#pragma unroll
            for (int reg = 0; reg < 4; ++reg)
                red[wr * 16 + q4 * 4 + reg][wc] = make_float2(rs[reg], rq[reg]);
        __syncthreads();

#pragma unroll
        for (int reg = 0; reg < 4; ++reg) {
            int row = wr * 16 + q4 * 4 + reg;
            float sum = red[row][0].x + red[row][1].x;
            float sq  = red[row][0].y + red[row][1].y;
            float mu  = sum * 0.00390625f;
            float var = sq * 0.00390625f - mu * mu;
            float rstd = rsqrtf(var + LN_EPS);
#pragma unroll
            for (int j = 0; j < 8; ++j) {
                int col = wc * 128 + j * 16 + r;
                float vv = (acc[j][reg] - mu) * rstd * g1[col] + b1[col];
                int cc = col >> 3, slot = cc ^ (row & 7);
                *(u16*)((char*)mln + row * 512 + slot * 16 + (col & 7) * 2) = f2bf(vv);
            }
        }
        __syncthreads();
    }

    {   // Phase B
        f32x4 acc2[2][8];
#pragma unroll
        for (int i = 0; i < 2; ++i)
#pragma unroll
            for (int j = 0; j < 8; ++j) acc2[i][j] = (f32x4){0.f, 0.f, 0.f, 0.f};

        for (int k0 = 0; k0 < 256; k0 += 32) {
#pragma unroll
            for (int g = 0; g < 8; ++g) {
                int row = w * 128 + g * 16 + srow;
                gload_lds(W1bt + (size_t)row * 256 + k0 + sch * 8, Bs + (w * 8 + g) * 512);
            }
            __syncthreads();
            bf16x8 af2[2];
#pragma unroll
            for (int i = 0; i < 2; ++i) {
                int ar = i * 16 + r;
                int c0 = (k0 >> 3) + ch;
                af2[i] = *(const bf16x8*)((const char*)mln + ar * 512 + ((c0 ^ (ar & 7)) * 16));
            }
#pragma unroll
            for (int j = 0; j < 8; ++j) {
                int br = w * 128 + j * 16 + r;
                bf16x8 bf = *(const bf16x8*)((const char*)Bs + br * 64 + ((ch ^ (r & 3)) * 16));
#pragma unroll
                for (int i = 0; i < 2; ++i)
                    acc2[i][j] = __builtin_amdgcn_mfma_f32_16x16x32_bf16(af2[i], bf, acc2[i][j], 0, 0, 0);
            }
            __syncthreads();
        }

#pragma unroll
        for (int i = 0; i < 2; ++i)
#pragma unroll
            for (int j = 0; j < 8; ++j) {
                int col = w * 128 + j * 16 + r;
#pragma unroll
                for (int reg = 0; reg < 4; ++reg) {
                    int row = i * 16 + q4 * 4 + reg;
                    size_t oidx = (size_t)(m0 + row) * 512 + col;
                    float vv = acc2[i][j][reg] + bf2f((u32)hx[oidx]);
                    vv = fmaxf(vv, 0.f);
                    h1b[oidx] = f2bf(vv);
                }
            }
    }
}

// ---------------------------------------------------------------------------
// GEMM (32 rows, N=256) + fused LayerNorm epilogue (W2+LN2+residual).
// ---------------------------------------------------------------------------
template<bool RESID, bool OUT_BF16>
__global__ __launch_bounds__(256) void gemm_ln_kernel(
    const u16* __restrict__ A, int lda,
    const u16* __restrict__ Bt, int ldb,
    const float* __restrict__ g, const float* __restrict__ b,
    const float* __restrict__ xres,
    void* __restrict__ Cout, int K)
{
    __shared__ __align__(16) u16 As[32 * 32];
    __shared__ __align__(16) u16 Bs[256 * 32];
    __shared__ float2 red[32][2];

    const int t  = threadIdx.x, l = t & 63, w = t >> 6;
    const int m0 = blockIdx.x * 32;
    const int wr = w >> 1, wc = w & 1;
    const int srow = l >> 2, sch = (l & 3) ^ (srow & 3);
    const int r = l & 15, ch = l >> 4, q4 = l >> 4;

    f32x4 acc[8];
#pragma unroll
    for (int j = 0; j < 8; ++j) acc[j] = (f32x4){0.f, 0.f, 0.f, 0.f};

    for (int k0 = 0; k0 < K; k0 += 32) {
        if (w < 2)
            gload_lds(A + (size_t)(m0 + w * 16 + srow) * lda + k0 + sch * 8, As + w * 512);
#pragma unroll
        for (int gg = 0; gg < 4; ++gg) {
            int grp = w * 4 + gg;
            gload_lds(Bt + (size_t)(grp * 16 + srow) * ldb + k0 + sch * 8, Bs + grp * 512);
        }
        __syncthreads();
        bf16x8 af = *(const bf16x8*)((const char*)As + (wr * 16 + r) * 64 + ((ch ^ (r & 3)) * 16));
#pragma unroll
        for (int j = 0; j < 8; ++j) {
            int br = wc * 128 + j * 16 + r;
            bf16x8 bf = *(const bf16x8*)((const char*)Bs + br * 64 + ((ch ^ (r & 3)) * 16));
            acc[j] = __builtin_amdgcn_mfma_f32_16x16x32_bf16(af, bf, acc[j], 0, 0, 0);
        }
        __syncthreads();
    }

    float rs[4], rq[4];
#pragma unroll
    for (int reg = 0; reg < 4; ++reg) {
        float s = 0.f, sq = 0.f;
#pragma unroll
        for (int j = 0; j < 8; ++j) { float vv = acc[j][reg]; s += vv; sq += vv * vv; }
        rs[reg] = s; rq[reg] = sq;
    }
#pragma unroll
    for (int off = 1; off <= 8; off <<= 1)
#pragma unroll
        for (int reg = 0; reg < 4; ++reg) {
            rs[reg] += __shfl_xor(rs[reg], off);
            rq[reg] += __shfl_xor(rq[reg], off);
        }
    if (r == 0)
#pragma unroll
        for (int reg = 0; reg < 4; ++reg)
            red[wr * 16 + q4 * 4 + reg][wc] = make_float2(rs[reg], rq[reg]);
    __syncthreads();

    float gj[8], bj[8];
#pragma unroll
    for (int j = 0; j < 8; ++j) {
        int col = wc * 128 + j * 16 + r;
        gj[j] = g[col]; bj[j] = b[col];
    }

#pragma unroll
    for (int reg = 0; reg < 4; ++reg) {
        int row = wr * 16 + q4 * 4 + reg;
        float sum = red[row][0].x + red[row][1].x;
        float sq  = red[row][0].y + red[row][1].y;
        float mu  = sum * 0.00390625f;
        float var = sq * 0.00390625f - mu * mu;
        float rstd = rsqrtf(var + LN_EPS);
#pragma unroll
        for (int j = 0; j < 8; ++j) {
            int col = wc * 128 + j * 16 + r;
            float vv = (acc[j][reg] - mu) * rstd * gj[j] + bj[j];
            size_t oidx = (size_t)(m0 + row) * 256 + col;
            if (RESID) vv += xres[oidx];
            if (OUT_BF16) ((u16*)Cout)[oidx] = f2bf(vv);
            else          ((float*)Cout)[oidx] = vv;
        }
    }
}

// ---------------------------------------------------------------------------
// Gathered attention, fp8 K/V (unchanged from r18 best).
// ---------------------------------------------------------------------------
__global__ __launch_bounds__(256, 8) void attn_kernel(
    const u16* __restrict__ q, const u8* __restrict__ k8,
    const u8* __restrict__ v8, const int* __restrict__ idx,
    u16* __restrict__ msg)
{
    const int t  = threadIdx.x;
    const int l  = t & 63;
    const int hp = t >> 6;
    const int bid = blockIdx.x;
    const int x8 = bid & 7, jj = bid >> 3;
    const int qi = (x8 < 4) ? (x8 * 1200 + jj) : (LQ + (x8 - 4) * 1200 + jj);
    const int n  = qi / LQ;
    const size_t srcbase8 = (size_t)n * LQ * 256;

    const int o = l >> 3;
    const int c = l & 7;

    const int* idxp = idx + (size_t)qi * 64;
    int rows[8];
#pragma unroll
    for (int i = 0; i < 8; ++i) rows[i] = idxp[i * 8 + o];

    const size_t hoff8 = (size_t)hp * 64 + c * 8;
    const size_t hoffq = (size_t)hp * 64 + c * 8;

    uint2 kd[8];
#pragma unroll
    for (int i = 0; i < 8; ++i)
        kd[i] = *(const uint2*)(k8 + srcbase8 + (size_t)rows[i] * 256 + hoff8);
    uint4 qc = *(const uint4*)(q + (size_t)qi * 256 + hoffq);

    float s[8];
#pragma unroll
    for (int i = 0; i < 8; ++i) {
        u32 k0l, k0h, k1l, k1h;
        fp8x4_to_2xf16(kd[i].x, k0l, k0h);
        fp8x4_to_2xf16(kd[i].y, k1l, k1h);
        float si = 0.f;
        si = dot2f16(k0l, qc.x, si);
        si = dot2f16(k0h, qc.y, si);
        si = dot2f16(k1l, qc.z, si);
        si = dot2f16(k1h, qc.w, si);
        si += __shfl_xor(si, 1);
        si += __shfl_xor(si, 2);
        s[i] = si * 0.17677669529663687f;
    }

    uint2 vd[8];
#pragma unroll
    for (int i = 0; i < 8; ++i)
        vd[i] = *(const uint2*)(v8 + srcbase8 + (size_t)rows[i] * 256 + hoff8);

    float mx = s[0];
#pragma unroll
    for (int i = 1; i < 8; ++i) mx = fmaxf(mx, s[i]);
    mx = fmaxf(mx, __shfl_xor(mx, 8));
    mx = fmaxf(mx, __shfl_xor(mx, 16));
    mx = fmaxf(mx, __shfl_xor(mx, 32));
    float p[8], sum = 0.f;
#pragma unroll
    for (int i = 0; i < 8; ++i) { p[i] = __expf(s[i] - mx); sum += p[i]; }
    sum += __shfl_xor(sum, 8);
    sum += __shfl_xor(sum, 16);
    sum += __shfl_xor(sum, 32);
    float inv = 1.f / sum;

    u32 A0 = 0, A1 = 0, A2 = 0, A3 = 0;
#pragma unroll
    for (int i = 0; i < 8; ++i) {
        float pi = p[i] * inv;
        u32 pp = pkrtz(pi, pi);
        u32 v0l, v0h, v1l, v1h;
        fp8x4_to_2xf16(vd[i].x, v0l, v0h);
        fp8x4_to_2xf16(vd[i].y, v1l, v1h);
        A0 = pk_fma16(pp, v0l, A0);
        A1 = pk_fma16(pp, v0h, A1);
        A2 = pk_fma16(pp, v1l, A2);
        A3 = pk_fma16(pp, v1h, A3);
    }

    const bool ob0 = (o & 1) != 0;
    const bool ob1 = (o & 2) != 0;
    {
        u32 t0 = ob0 ? A0 : A2;
        u32 t1 = ob0 ? A1 : A3;
        t0 = __shfl_xor((int)t0, 8);
        t1 = __shfl_xor((int)t1, 8);
        A0 = pk_add16(ob0 ? A2 : A0, t0);
        A1 = pk_add16(ob0 ? A3 : A1, t1);
    }
    {
        u32 u0 = ob1 ? A0 : A1;
        u0 = __shfl_xor((int)u0, 16);
        A0 = pk_add16(ob1 ? A1 : A0, u0);
    }
    A0 = pk_add16(A0, (u32)__shfl_xor((int)A0, 32));

    if (o < 4) {
        int j = 2 * (o & 1) + ((o >> 1) & 1);
        f16x2 hv = __builtin_bit_cast(f16x2, A0);
        u32 packed = (u32)f2bf((float)hv.x) | ((u32)f2bf((float)hv.y) << 16);
        *(u32*)(msg + (size_t)qi * 256 + hp * 64 + c * 8 + j * 2) = packed;
    }
}

// ---------------------------------------------------------------------------
extern "C" void kernel_launch(void* const* d_in, const int* in_sizes, int n_in,
                              void* d_out, int out_size, void* d_ws, size_t ws_size,
                              hipStream_t stream)
{
    const float* x      = (const float*)d_in[0];
    const float* source = (const float*)d_in[1];
    const int*   eidx   = (const int*)d_in[2];
    const float* Wq     = (const float*)d_in[3];
    const float* Wk     = (const float*)d_in[4];
    const float* Wv     = (const float*)d_in[5];
    const float* Wm     = (const float*)d_in[6];
    const float* W1     = (const float*)d_in[7];
    const float* W2     = (const float*)d_in[8];
    const float* g1     = (const float*)d_in[9];
    const float* b1     = (const float*)d_in[10];
    const float* g2     = (const float*)d_in[11];
    const float* b2     = (const float*)d_in[12];
    float* out = (float*)d_out;

    char* ws = (char*)d_ws;
    const size_t SZB = (size_t)MROWS * 256 * 2;    // 4.9 MB
    u16* qb     = (u16*)(ws);                      // f16 [9600][256]
    u8*  kb8    = (u8*)(ws + SZB);                 // fp8 [9600][256]
    u8*  vb8    = (u8*)(ws + SZB + SZB / 2);       // fp8 [9600][256]
    u16* msgb   = (u16*)(ws + 2 * SZB);            // bf16 attn output
    u16* hx     = (u16*)(ws + 3 * SZB);            // bf16 [9600][512] x@W1_top
    u16* h1b    = (u16*)(ws + 5 * SZB);            // bf16 [9600][512]
    u16* xh     = (u16*)(ws + 7 * SZB);            // f16 [9600][256]
    u16* sh     = (u16*)(ws + 8 * SZB);            // f16 [9600][256]
    u16* Wqkvh  = (u16*)(ws + 9 * SZB);            // f16 [1280][256]
    u16* Wmt    = Wqkvh + 1280 * 256;              // bf16 [256][256]
    u16* W1bt   = Wmt + 256 * 256;                 // bf16 [512][256]
    u16* W2t    = W1bt + 512 * 256;                // bf16 [256][512]

    dim3 blk(256);

    // input casts + weight transposes
    prep_kernel<<<dim3(7360), blk, 0, stream>>>(x, source, Wq, Wk, Wv, Wm, W1, W2,
                                                xh, sh, Wqkvh, Wmt, W1bt, W2t);

    // q|k|v|h_top from f16 inputs, BN=256 (750 blocks), k/v -> fp8
    qkvh_kernel<<<dim3(5, 150), blk, 0, stream>>>(xh, sh, Wqkvh, qb, kb8, vb8, hx);

    // gathered attention (fp8 K/V) -> msg (bf16)
    attn_kernel<<<dim3(MROWS), blk, 0, stream>>>(qb, kb8, vb8, eidx, msgb);

    // Wm+LN1+W1_bot fused (msgln stays in LDS) -> h1b
    wm_w1_kernel<<<dim3(300), blk, 0, stream>>>(msgb, Wmt, W1bt, hx, g1, b1, h1b);

    // h1 @ W2 + LN2 + residual -> fp32 out
    gemm_ln_kernel<true, false><<<dim3(300), blk, 0, stream>>>(
        h1b, 512, W2t, 512, g2, b2, x, out, 512);
}